// Round 12
// baseline (146.639 us; speedup 1.0000x reference)
//
#include <hip/hip_runtime.h>

// GCN 2-layer forward, aggregate-first + bf16 prescaled gather, FEATURE-SPLIT
// so each gather pass's working set (3.2 MB) fits the 4 MB per-XCD L2:
//   xh_lo[r] = bf16(dinv_r * x_r[0:32]), xh_hi[r] = bf16(dinv_r * x_r[32:64])
//   S_c = dinv_c * sum_{r in N(c)+self} xh_r     (fp32 accum, two passes)
//   z_c = relu( S_c @ W + b )
// CSR via counting sort into fixed-capacity bucket regions (bucket = col>>8).

#define DF 64
#define XS_LD 68
#define ECHUNK 4096
#define BCAP 5120        // bucket region capacity (mean 4096 + 16 sigma)

typedef float vf4 __attribute__((ext_vector_type(4)));   // for nontemporal builtins

__device__ __forceinline__ unsigned short f2bf(float f) {
  union { float f; unsigned int u; } c; c.f = f;
  unsigned int r = c.u + 0x7FFFu + ((c.u >> 16) & 1u);   // RNE
  return (unsigned short)(r >> 16);
}
__device__ __forceinline__ float bflo(unsigned int u) {
  union { unsigned int u; float f; } c; c.u = u << 16; return c.f;
}
__device__ __forceinline__ float bfhi(unsigned int u) {
  union { unsigned int u; float f; } c; c.u = u & 0xFFFF0000u; return c.f;
}

// ---- stage 0: init bucket cursors ----
__global__ void init_cur_k(int* __restrict__ gcursor) {
  gcursor[threadIdx.x] = threadIdx.x * BCAP;
}

// ---- stage 1: partition edges into bucket regions (direct-index flush) ----
__global__ __launch_bounds__(256) void part_k(
    const int* __restrict__ rows, const int* __restrict__ cols,
    int* __restrict__ gcursor, unsigned int* __restrict__ bfile, int e_cnt)
{
  __shared__ int h[256];
  __shared__ int p[256];
  __shared__ int lb[256];
  __shared__ int cur[256];
  __shared__ int gb[256];
  __shared__ unsigned int buf[ECHUNK];
  const int tid = threadIdx.x;
  h[tid] = 0; __syncthreads();

  const int e0 = blockIdx.x * ECHUNK;
  const int m  = min(ECHUNK, e_cnt - e0);
  unsigned int pk[ECHUNK / 256];
  int bk[ECHUNK / 256];
#pragma unroll
  for (int j = 0; j < ECHUNK / 256; ++j) {
    int idx = j * 256 + tid;
    if (idx < m) {
      int c = cols[e0 + idx];
      int r = rows[e0 + idx];
      bk[j] = c >> 8;
      // bucket in [31:24], local col in [23:16], row in [15:0]
      pk[j] = ((unsigned int)bk[j] << 24) | ((unsigned int)(c & 255) << 16) | (unsigned int)r;
      atomicAdd(&h[bk[j]], 1);
    } else bk[j] = -1;
  }
  __syncthreads();

  const int myc = h[tid];
  p[tid] = myc; __syncthreads();
  for (int off = 1; off < 256; off <<= 1) {
    int t = (tid >= off) ? p[tid - off] : 0;
    __syncthreads();
    p[tid] += t;
    __syncthreads();
  }
  const int ex = p[tid] - myc;
  lb[tid] = ex; cur[tid] = ex;
  if (myc > 0) gb[tid] = atomicAdd(&gcursor[tid], myc);
  __syncthreads();

#pragma unroll
  for (int j = 0; j < ECHUNK / 256; ++j)
    if (bk[j] >= 0) { int pos = atomicAdd(&cur[bk[j]], 1); buf[pos] = pk[j]; }
  __syncthreads();

  for (int i = tid; i < m; i += 256) {
    unsigned int v = buf[i];
    int b = (int)(v >> 24);
    bfile[gb[b] + (i - lb[b])] = v;
  }
}

// ---- stage 2: per-bucket counting sort -> csr_src, cnt, base, dinv ----
__global__ __launch_bounds__(256) void bucket_k(
    const unsigned int* __restrict__ bfile, const int* __restrict__ gcursor,
    int* __restrict__ csr_src, int* __restrict__ basep, int* __restrict__ cntp,
    float* __restrict__ dinv, int n)
{
  __shared__ unsigned int ein[BCAP];
  __shared__ unsigned short eout[BCAP];
  __shared__ int h[256];
  __shared__ int p[256];
  __shared__ int cur[256];
  const int tid = threadIdx.x;
  const int b   = blockIdx.x;
  const int s   = b * BCAP;
  int L = gcursor[b] - s;
  if (L > BCAP) L = BCAP;

  for (int i = tid; i < L; i += 256) ein[i] = bfile[s + i];
  h[tid] = 0; __syncthreads();
  for (int i = tid; i < L; i += 256) atomicAdd(&h[(ein[i] >> 16) & 255], 1);
  __syncthreads();

  const int myc = h[tid];
  p[tid] = myc; __syncthreads();
  for (int off = 1; off < 256; off <<= 1) {
    int t = (tid >= off) ? p[tid - off] : 0;
    __syncthreads();
    p[tid] += t;
    __syncthreads();
  }
  const int ex = p[tid] - myc;
  cur[tid] = ex;
  __syncthreads();

  for (int i = tid; i < L; i += 256) {
    unsigned int pk = ein[i];
    int pos = atomicAdd(&cur[(pk >> 16) & 255], 1);
    eout[pos] = (unsigned short)(pk & 0xffffu);
  }
  __syncthreads();

  for (int i = tid; i < L; i += 256) csr_src[s + i] = (int)eout[i];

  const int node = b * 256 + tid;
  if (node < n) {
    basep[node] = s + ex;
    cntp[node]  = myc;
    dinv[node]  = rsqrtf(1.0f + (float)myc);
  }
}

// ---- stage 3: x -> xh_lo / xh_hi = bf16(dinv*x), split halves ----
__global__ __launch_bounds__(256) void conv_k(
    const float* __restrict__ x, const float* __restrict__ dinv,
    uint4* __restrict__ xlo, uint4* __restrict__ xhi, int n)
{
  int t = blockIdx.x * blockDim.x + threadIdx.x;   // n*8 slots, 8 feats each
  if (t >= n * 8) return;
  const int node = t >> 3, q = t & 7;
  const float dv = dinv[node];
  float4 v0 = ((const float4*)x)[(size_t)t * 2 + 0];
  float4 v1 = ((const float4*)x)[(size_t)t * 2 + 1];
  uint4 o;
  o.x = (unsigned int)f2bf(dv * v0.x) | ((unsigned int)f2bf(dv * v0.y) << 16);
  o.y = (unsigned int)f2bf(dv * v0.z) | ((unsigned int)f2bf(dv * v0.w) << 16);
  o.z = (unsigned int)f2bf(dv * v1.x) | ((unsigned int)f2bf(dv * v1.y) << 16);
  o.w = (unsigned int)f2bf(dv * v1.z) | ((unsigned int)f2bf(dv * v1.w) << 16);
  if (q < 4) xlo[(size_t)node * 4 + q] = o;
  else       xhi[(size_t)node * 4 + (q - 4)] = o;
}

// ---- gather pass A: lo half (64B rows, L2-resident) -> S_lo (nt store) ----
__global__ __launch_bounds__(256) void gatherA_k(
    const uint4* __restrict__ inlo, const int* __restrict__ csr_src,
    const int* __restrict__ basep, const int* __restrict__ cntp,
    const float* __restrict__ dinv, float* __restrict__ Slo, int n)
{
  const int nl = threadIdx.x >> 2;     // 0..63
  const int q  = threadIdx.x & 3;      // 0..3, feats q*8..q*8+7
  const int node = blockIdx.x * 64 + nl;
  if (node >= n) return;

  float a[8], b[8];
  {
    uint4 v = inlo[(size_t)node * 4 + q];   // self (prescaled)
    a[0] = bflo(v.x); a[1] = bfhi(v.x); a[2] = bflo(v.y); a[3] = bfhi(v.y);
    a[4] = bflo(v.z); a[5] = bfhi(v.z); a[6] = bflo(v.w); a[7] = bfhi(v.w);
#pragma unroll
    for (int j = 0; j < 8; ++j) b[j] = 0.f;
  }
  const int s = basep[node], c = cntp[node];
  int k = 0;
  for (; k + 4 <= c; k += 4) {
    int r0 = __builtin_nontemporal_load(csr_src + s + k + 0);
    int r1 = __builtin_nontemporal_load(csr_src + s + k + 1);
    int r2 = __builtin_nontemporal_load(csr_src + s + k + 2);
    int r3 = __builtin_nontemporal_load(csr_src + s + k + 3);
    uint4 v0 = inlo[(size_t)r0 * 4 + q];
    uint4 v1 = inlo[(size_t)r1 * 4 + q];
    uint4 v2 = inlo[(size_t)r2 * 4 + q];
    uint4 v3 = inlo[(size_t)r3 * 4 + q];
    a[0] += bflo(v0.x) + bflo(v1.x); a[1] += bfhi(v0.x) + bfhi(v1.x);
    a[2] += bflo(v0.y) + bflo(v1.y); a[3] += bfhi(v0.y) + bfhi(v1.y);
    a[4] += bflo(v0.z) + bflo(v1.z); a[5] += bfhi(v0.z) + bfhi(v1.z);
    a[6] += bflo(v0.w) + bflo(v1.w); a[7] += bfhi(v0.w) + bfhi(v1.w);
    b[0] += bflo(v2.x) + bflo(v3.x); b[1] += bfhi(v2.x) + bfhi(v3.x);
    b[2] += bflo(v2.y) + bflo(v3.y); b[3] += bfhi(v2.y) + bfhi(v3.y);
    b[4] += bflo(v2.z) + bflo(v3.z); b[5] += bfhi(v2.z) + bfhi(v3.z);
    b[6] += bflo(v2.w) + bflo(v3.w); b[7] += bfhi(v2.w) + bfhi(v3.w);
  }
  for (; k < c; ++k) {
    int r = __builtin_nontemporal_load(csr_src + s + k);
    uint4 v = inlo[(size_t)r * 4 + q];
    a[0] += bflo(v.x); a[1] += bfhi(v.x); a[2] += bflo(v.y); a[3] += bfhi(v.y);
    a[4] += bflo(v.z); a[5] += bfhi(v.z); a[6] += bflo(v.w); a[7] += bfhi(v.w);
  }
  const float dv = dinv[node];
  vf4 o0 = {dv*(a[0]+b[0]), dv*(a[1]+b[1]), dv*(a[2]+b[2]), dv*(a[3]+b[3])};
  vf4 o1 = {dv*(a[4]+b[4]), dv*(a[5]+b[5]), dv*(a[6]+b[6]), dv*(a[7]+b[7])};
  __builtin_nontemporal_store(o0, (vf4*)(Slo + (size_t)node * 32 + q * 8 + 0));
  __builtin_nontemporal_store(o1, (vf4*)(Slo + (size_t)node * 32 + q * 8 + 4));
}

// ---- gather pass B + GEMM: hi half gather, S assembled in LDS, 64x64 GEMM,
//      bias+relu. OUTBF=1: bf16 prescaled split output; else fp32. ----
template<int OUTBF>
__global__ __launch_bounds__(256) void gatherB_gemm_k(
    const uint4* __restrict__ inhi, const float* __restrict__ Slo,
    const float* __restrict__ W, const float* __restrict__ bias,
    const int* __restrict__ csr_src, const int* __restrict__ basep,
    const int* __restrict__ cntp, const float* __restrict__ dinv,
    void* __restrict__ out0, void* __restrict__ out1, int n)
{
  __shared__ float Ws[DF * XS_LD];
  __shared__ float Ss[64 * XS_LD];
  const int tid = threadIdx.x;

#pragma unroll
  for (int i = 0; i < 4; ++i) {
    const int f4 = tid + 256 * i;
    const int kk = f4 >> 4;
    const int c0 = (f4 & 15) * 4;
    *(float4*)(Ws + kk * XS_LD + c0) = *(const float4*)(W + (size_t)f4 * 4);
  }

  const int nl = tid >> 2;             // 0..63
  const int q  = tid & 3;              // 0..3
  const int node = blockIdx.x * 64 + nl;

  if (node < n) {
    float a[8], b[8];
    {
      uint4 v = inhi[(size_t)node * 4 + q];
      a[0] = bflo(v.x); a[1] = bfhi(v.x); a[2] = bflo(v.y); a[3] = bfhi(v.y);
      a[4] = bflo(v.z); a[5] = bfhi(v.z); a[6] = bflo(v.w); a[7] = bfhi(v.w);
#pragma unroll
      for (int j = 0; j < 8; ++j) b[j] = 0.f;
    }
    const int s = basep[node], c = cntp[node];
    int k = 0;
    for (; k + 4 <= c; k += 4) {
      int r0 = __builtin_nontemporal_load(csr_src + s + k + 0);
      int r1 = __builtin_nontemporal_load(csr_src + s + k + 1);
      int r2 = __builtin_nontemporal_load(csr_src + s + k + 2);
      int r3 = __builtin_nontemporal_load(csr_src + s + k + 3);
      uint4 v0 = inhi[(size_t)r0 * 4 + q];
      uint4 v1 = inhi[(size_t)r1 * 4 + q];
      uint4 v2 = inhi[(size_t)r2 * 4 + q];
      uint4 v3 = inhi[(size_t)r3 * 4 + q];
      a[0] += bflo(v0.x) + bflo(v1.x); a[1] += bfhi(v0.x) + bfhi(v1.x);
      a[2] += bflo(v0.y) + bflo(v1.y); a[3] += bfhi(v0.y) + bfhi(v1.y);
      a[4] += bflo(v0.z) + bflo(v1.z); a[5] += bfhi(v0.z) + bfhi(v1.z);
      a[6] += bflo(v0.w) + bflo(v1.w); a[7] += bfhi(v0.w) + bfhi(v1.w);
      b[0] += bflo(v2.x) + bflo(v3.x); b[1] += bfhi(v2.x) + bfhi(v3.x);
      b[2] += bflo(v2.y) + bflo(v3.y); b[3] += bfhi(v2.y) + bfhi(v3.y);
      b[4] += bflo(v2.z) + bflo(v3.z); b[5] += bfhi(v2.z) + bfhi(v3.z);
      b[6] += bflo(v2.w) + bflo(v3.w); b[7] += bfhi(v2.w) + bfhi(v3.w);
    }
    for (; k < c; ++k) {
      int r = __builtin_nontemporal_load(csr_src + s + k);
      uint4 v = inhi[(size_t)r * 4 + q];
      a[0] += bflo(v.x); a[1] += bfhi(v.x); a[2] += bflo(v.y); a[3] += bfhi(v.y);
      a[4] += bflo(v.z); a[5] += bfhi(v.z); a[6] += bflo(v.w); a[7] += bfhi(v.w);
    }
    const float dv = dinv[node];
    // hi half -> cols 32..63
    float4 h0 = make_float4(dv*(a[0]+b[0]), dv*(a[1]+b[1]), dv*(a[2]+b[2]), dv*(a[3]+b[3]));
    float4 h1 = make_float4(dv*(a[4]+b[4]), dv*(a[5]+b[5]), dv*(a[6]+b[6]), dv*(a[7]+b[7]));
    *(float4*)(Ss + nl * XS_LD + 32 + q * 8 + 0) = h0;
    *(float4*)(Ss + nl * XS_LD + 32 + q * 8 + 4) = h1;
    // lo half from Slo
    vf4 l0 = __builtin_nontemporal_load((const vf4*)(Slo + (size_t)node * 32 + q * 8 + 0));
    vf4 l1 = __builtin_nontemporal_load((const vf4*)(Slo + (size_t)node * 32 + q * 8 + 4));
    *(vf4*)(Ss + nl * XS_LD + q * 8 + 0) = l0;
    *(vf4*)(Ss + nl * XS_LD + q * 8 + 4) = l1;
  }
  __syncthreads();

  // GEMM in two sub-passes of 32 nodes; 8 output feats per lane
  const int q2 = tid & 7;
#pragma unroll
  for (int sub = 0; sub < 2; ++sub) {
    const int nl2 = (tid >> 3) + 32 * sub;
    const int node2 = blockIdx.x * 64 + nl2;
    float4 o0 = ((const float4*)bias)[q2 * 2 + 0];
    float4 o1 = ((const float4*)bias)[q2 * 2 + 1];
#pragma unroll 16
    for (int k = 0; k < DF; ++k) {
      const float sk = Ss[nl2 * XS_LD + k];
      const float4 w0 = *(const float4*)(Ws + k * XS_LD + q2 * 8 + 0);
      const float4 w1 = *(const float4*)(Ws + k * XS_LD + q2 * 8 + 4);
      o0.x += sk * w0.x; o0.y += sk * w0.y; o0.z += sk * w0.z; o0.w += sk * w0.w;
      o1.x += sk * w1.x; o1.y += sk * w1.y; o1.z += sk * w1.z; o1.w += sk * w1.w;
    }
    if (node2 < n) {
      o0.x = fmaxf(o0.x, 0.f); o0.y = fmaxf(o0.y, 0.f);
      o0.z = fmaxf(o0.z, 0.f); o0.w = fmaxf(o0.w, 0.f);
      o1.x = fmaxf(o1.x, 0.f); o1.y = fmaxf(o1.y, 0.f);
      o1.z = fmaxf(o1.z, 0.f); o1.w = fmaxf(o1.w, 0.f);
      if (OUTBF) {
        const float dv2 = dinv[node2];
        uint4 u;
        u.x = (unsigned int)f2bf(dv2 * o0.x) | ((unsigned int)f2bf(dv2 * o0.y) << 16);
        u.y = (unsigned int)f2bf(dv2 * o0.z) | ((unsigned int)f2bf(dv2 * o0.w) << 16);
        u.z = (unsigned int)f2bf(dv2 * o1.x) | ((unsigned int)f2bf(dv2 * o1.y) << 16);
        u.w = (unsigned int)f2bf(dv2 * o1.z) | ((unsigned int)f2bf(dv2 * o1.w) << 16);
        if (q2 < 4) ((uint4*)out0)[(size_t)node2 * 4 + q2] = u;
        else        ((uint4*)out1)[(size_t)node2 * 4 + (q2 - 4)] = u;
      } else {
        ((float4*)out0)[(size_t)node2 * 16 + q2 * 2 + 0] = o0;
        ((float4*)out0)[(size_t)node2 * 16 + q2 * 2 + 1] = o1;
      }
    }
  }
}

extern "C" void kernel_launch(void* const* d_in, const int* in_sizes, int n_in,
                              void* d_out, int out_size, void* d_ws, size_t ws_size,
                              hipStream_t stream) {
  const float* x  = (const float*)d_in[0];
  const float* W1 = (const float*)d_in[1];
  const float* b1 = (const float*)d_in[2];
  const float* W2 = (const float*)d_in[3];
  const float* b2 = (const float*)d_in[4];
  const int*   ei = (const int*)d_in[5];

  const int n = in_sizes[0] / DF;        // 50000
  const int E = in_sizes[5] / 2;         // 800000
  const int* rows = ei;
  const int* cols = ei + E;
  const int nb = (n + 255) >> 8;         // 196 buckets
  const int eblocks = (E + ECHUNK - 1) / ECHUNK;

  char* w = (char*)d_ws;
  size_t off = 0;
  auto alloc = [&](size_t bytes) { char* p = w + off; off = (off + bytes + 255) & ~(size_t)255; return p; };
  float* dinv    = (float*)alloc((size_t)n * 4);
  int*   cntp    = (int*)  alloc((size_t)n * 4);
  int*   basep   = (int*)  alloc((size_t)n * 4);
  int*   gcursor = (int*)  alloc(256 * 4);
  unsigned int* bfile = (unsigned int*)alloc((size_t)nb * BCAP * 4);
  int*   csr_src = (int*)  alloc((size_t)nb * BCAP * 4);
  uint4* xh_lo   = (uint4*)alloc((size_t)n * 64);       // 3.2 MB
  uint4* xh_hi   = (uint4*)alloc((size_t)n * 64);       // 3.2 MB
  uint4* zh_lo   = (uint4*)alloc((size_t)n * 64);
  uint4* zh_hi   = (uint4*)alloc((size_t)n * 64);
  float* Slo     = (float*)alloc((size_t)n * 32 * 4);   // 6.4 MB

  const int b256 = 256;

  // ---- CSR build + dinv ----
  init_cur_k<<<1, 256, 0, stream>>>(gcursor);
  part_k<<<eblocks, b256, 0, stream>>>(rows, cols, gcursor, bfile, E);
  bucket_k<<<nb, b256, 0, stream>>>(bfile, gcursor, csr_src, basep, cntp, dinv, n);

  // ---- x -> split prescaled bf16 ----
  conv_k<<<(n * 8 + 255) / 256, b256, 0, stream>>>(x, dinv, xh_lo, xh_hi, n);

  const int gblocks = (n + 63) / 64;    // 782

  // ---- layer 1 ----
  gatherA_k<<<gblocks, b256, 0, stream>>>(xh_lo, csr_src, basep, cntp, dinv, Slo, n);
  gatherB_gemm_k<1><<<gblocks, b256, 0, stream>>>(xh_hi, Slo, W1, b1, csr_src, basep, cntp, dinv, zh_lo, zh_hi, n);
  // ---- layer 2 ----
  gatherA_k<<<gblocks, b256, 0, stream>>>(zh_lo, csr_src, basep, cntp, dinv, Slo, n);
  gatherB_gemm_k<0><<<gblocks, b256, 0, stream>>>(zh_hi, Slo, W2, b2, csr_src, basep, cntp, dinv, d_out, nullptr, n);
}

// Round 13
// 102.153 us; speedup vs baseline: 1.4355x; 1.4355x over previous
//
#include <hip/hip_runtime.h>

// GCN 2-layer forward, aggregate-first + bf16 dinv-prescaled gather +
// DEGREE-SORTED node permutation (equalizes gather-loop trip count per wave):
//   xh[r] = bf16(dinv_r * in_r);  S_c = dinv_c * sum xh_r;  z = relu(S@W + b)
// CSR via counting sort into fixed-capacity bucket regions (bucket = col>>8).

#define DF 64
#define XS_LD 68
#define ECHUNK 4096
#define BCAP 5120        // bucket region capacity (mean 4096 + 16 sigma)

__device__ __forceinline__ unsigned short f2bf(float f) {
  union { float f; unsigned int u; } c; c.f = f;
  unsigned int r = c.u + 0x7FFFu + ((c.u >> 16) & 1u);   // RNE
  return (unsigned short)(r >> 16);
}
__device__ __forceinline__ float bflo(unsigned int u) {
  union { unsigned int u; float f; } c; c.u = u << 16; return c.f;
}
__device__ __forceinline__ float bfhi(unsigned int u) {
  union { unsigned int u; float f; } c; c.u = u & 0xFFFF0000u; return c.f;
}

// ---- stage 0: init bucket cursors ----
__global__ void init_cur_k(int* __restrict__ gcursor) {
  gcursor[threadIdx.x] = threadIdx.x * BCAP;
}

// ---- stage 1: partition edges into bucket regions (direct-index flush) ----
__global__ __launch_bounds__(256) void part_k(
    const int* __restrict__ rows, const int* __restrict__ cols,
    int* __restrict__ gcursor, unsigned int* __restrict__ bfile, int e_cnt)
{
  __shared__ int h[256];
  __shared__ int p[256];
  __shared__ int lb[256];
  __shared__ int cur[256];
  __shared__ int gb[256];
  __shared__ unsigned int buf[ECHUNK];
  const int tid = threadIdx.x;
  h[tid] = 0; __syncthreads();

  const int e0 = blockIdx.x * ECHUNK;
  const int m  = min(ECHUNK, e_cnt - e0);
  unsigned int pk[ECHUNK / 256];
  int bk[ECHUNK / 256];
#pragma unroll
  for (int j = 0; j < ECHUNK / 256; ++j) {
    int idx = j * 256 + tid;
    if (idx < m) {
      int c = cols[e0 + idx];
      int r = rows[e0 + idx];
      bk[j] = c >> 8;
      // bucket in [31:24], local col in [23:16], row in [15:0]
      pk[j] = ((unsigned int)bk[j] << 24) | ((unsigned int)(c & 255) << 16) | (unsigned int)r;
      atomicAdd(&h[bk[j]], 1);
    } else bk[j] = -1;
  }
  __syncthreads();

  const int myc = h[tid];
  p[tid] = myc; __syncthreads();
  for (int off = 1; off < 256; off <<= 1) {
    int t = (tid >= off) ? p[tid - off] : 0;
    __syncthreads();
    p[tid] += t;
    __syncthreads();
  }
  const int ex = p[tid] - myc;
  lb[tid] = ex; cur[tid] = ex;
  if (myc > 0) gb[tid] = atomicAdd(&gcursor[tid], myc);
  __syncthreads();

#pragma unroll
  for (int j = 0; j < ECHUNK / 256; ++j)
    if (bk[j] >= 0) { int pos = atomicAdd(&cur[bk[j]], 1); buf[pos] = pk[j]; }
  __syncthreads();

  for (int i = tid; i < m; i += 256) {
    unsigned int v = buf[i];
    int b = (int)(v >> 24);
    bfile[gb[b] + (i - lb[b])] = v;
  }
}

// ---- stage 2: per-bucket counting sort -> csr_src, cnt, base, dinv, perm ----
__global__ __launch_bounds__(256) void bucket_k(
    const unsigned int* __restrict__ bfile, const int* __restrict__ gcursor,
    int* __restrict__ csr_src, int* __restrict__ basep, int* __restrict__ cntp,
    float* __restrict__ dinv, int* __restrict__ perm, int n)
{
  __shared__ unsigned int ein[BCAP];
  __shared__ unsigned short eout[BCAP];
  __shared__ int h[256];
  __shared__ int p[256];
  __shared__ int cur[256];
  __shared__ int h2[64];     // degree-class histogram (cap 63)
  __shared__ int c2[64];
  const int tid = threadIdx.x;
  const int b   = blockIdx.x;
  const int s   = b * BCAP;
  int L = gcursor[b] - s;
  if (L > BCAP) L = BCAP;

  for (int i = tid; i < L; i += 256) ein[i] = bfile[s + i];
  h[tid] = 0;
  if (tid < 64) h2[tid] = 0;
  __syncthreads();
  for (int i = tid; i < L; i += 256) atomicAdd(&h[(ein[i] >> 16) & 255], 1);
  __syncthreads();

  const int myc = h[tid];
  p[tid] = myc; __syncthreads();
  for (int off = 1; off < 256; off <<= 1) {
    int t = (tid >= off) ? p[tid - off] : 0;
    __syncthreads();
    p[tid] += t;
    __syncthreads();
  }
  const int ex = p[tid] - myc;
  cur[tid] = ex;
  __syncthreads();

  for (int i = tid; i < L; i += 256) {
    unsigned int pk = ein[i];
    int pos = atomicAdd(&cur[(pk >> 16) & 255], 1);
    eout[pos] = (unsigned short)(pk & 0xffffu);
  }
  __syncthreads();

  for (int i = tid; i < L; i += 256) csr_src[s + i] = (int)eout[i];

  const int node = b * 256 + tid;
  const bool valid = (node < n);
  int cap = 0;
  if (valid) {
    basep[node] = s + ex;
    cntp[node]  = myc;
    dinv[node]  = rsqrtf(1.0f + (float)myc);
    cap = min(myc, 63);
    atomicAdd(&h2[cap], 1);
  }
  __syncthreads();
  if (tid == 0) {                         // tiny serial scan of 64 bins
    int run = 0;
    for (int i = 0; i < 64; ++i) { c2[i] = run; run += h2[i]; }
  }
  __syncthreads();
  if (valid) {
    int r = atomicAdd(&c2[cap], 1);       // rank within bucket, degree-sorted
    perm[b * 256 + r] = node;
  }
}

// ---- stage 3: xh = bf16(dinv * x), packed 8 per thread ----
__global__ __launch_bounds__(256) void conv_k(
    const float* __restrict__ x, const float* __restrict__ dinv,
    uint4* __restrict__ xh, int n)
{
  int t = blockIdx.x * blockDim.x + threadIdx.x;   // over n*8 slots
  if (t >= n * 8) return;
  const float dv = dinv[t >> 3];
  float4 v0 = ((const float4*)x)[(size_t)t * 2 + 0];
  float4 v1 = ((const float4*)x)[(size_t)t * 2 + 1];
  uint4 o;
  o.x = (unsigned int)f2bf(dv * v0.x) | ((unsigned int)f2bf(dv * v0.y) << 16);
  o.y = (unsigned int)f2bf(dv * v0.z) | ((unsigned int)f2bf(dv * v0.w) << 16);
  o.z = (unsigned int)f2bf(dv * v1.x) | ((unsigned int)f2bf(dv * v1.y) << 16);
  o.w = (unsigned int)f2bf(dv * v1.z) | ((unsigned int)f2bf(dv * v1.w) << 16);
  xh[t] = o;
}

// ---- fused layer: bf16 gather (8 lanes/node, 16B/lane), fp32 accum,
//      S tile -> LDS, in-block GEMM + bias + relu. 32 nodes / 256-thr block.
//      Nodes taken in degree-sorted perm order (minimizes wave divergence).
//      OUTBF=1: write bf16(dinv_c * relu) for next layer; else fp32. ----
template<int OUTBF>
__global__ __launch_bounds__(256) void fused_layer_k(
    const uint4* __restrict__ inh, const float* __restrict__ W,
    const float* __restrict__ bias, const int* __restrict__ csr_src,
    const int* __restrict__ basep, const int* __restrict__ cntp,
    const float* __restrict__ dinv, const int* __restrict__ perm,
    void* __restrict__ outp, int n)
{
  __shared__ float Ws[DF * XS_LD];
  __shared__ float Ss[32 * XS_LD];
  __shared__ int   nd[32];
  const int tid = threadIdx.x;

#pragma unroll
  for (int i = 0; i < 4; ++i) {
    const int f4 = tid + 256 * i;
    const int k  = f4 >> 4;
    const int c0 = (f4 & 15) * 4;
    *(float4*)(Ws + k * XS_LD + c0) = *(const float4*)(W + (size_t)f4 * 4);
  }

  const int nl   = tid >> 3;            // 0..31
  const int q    = tid & 7;             // 0..7
  const int idx  = blockIdx.x * 32 + nl;
  const bool valid = (idx < n);
  const int node = valid ? perm[idx] : 0;
  if (q == 0) nd[nl] = node;
  float dv = 0.f;

  if (valid) {
    float a[8] = {0,0,0,0,0,0,0,0};
    float b2[8] = {0,0,0,0,0,0,0,0};
    dv = dinv[node];
    {
      uint4 v = inh[(size_t)node * 8 + q];          // self term (prescaled)
      a[0] += bflo(v.x); a[1] += bfhi(v.x); a[2] += bflo(v.y); a[3] += bfhi(v.y);
      a[4] += bflo(v.z); a[5] += bfhi(v.z); a[6] += bflo(v.w); a[7] += bfhi(v.w);
    }
    const int s = basep[node], c = cntp[node];
    int k = 0;
    for (; k + 4 <= c; k += 4) {
      int r0 = __builtin_nontemporal_load(csr_src + s + k + 0);
      int r1 = __builtin_nontemporal_load(csr_src + s + k + 1);
      int r2 = __builtin_nontemporal_load(csr_src + s + k + 2);
      int r3 = __builtin_nontemporal_load(csr_src + s + k + 3);
      uint4 v0 = inh[(size_t)r0 * 8 + q];
      uint4 v1 = inh[(size_t)r1 * 8 + q];
      uint4 v2 = inh[(size_t)r2 * 8 + q];
      uint4 v3 = inh[(size_t)r3 * 8 + q];
      a[0]  += bflo(v0.x) + bflo(v1.x); a[1]  += bfhi(v0.x) + bfhi(v1.x);
      a[2]  += bflo(v0.y) + bflo(v1.y); a[3]  += bfhi(v0.y) + bfhi(v1.y);
      a[4]  += bflo(v0.z) + bflo(v1.z); a[5]  += bfhi(v0.z) + bfhi(v1.z);
      a[6]  += bflo(v0.w) + bflo(v1.w); a[7]  += bfhi(v0.w) + bfhi(v1.w);
      b2[0] += bflo(v2.x) + bflo(v3.x); b2[1] += bfhi(v2.x) + bfhi(v3.x);
      b2[2] += bflo(v2.y) + bflo(v3.y); b2[3] += bfhi(v2.y) + bfhi(v3.y);
      b2[4] += bflo(v2.z) + bflo(v3.z); b2[5] += bfhi(v2.z) + bfhi(v3.z);
      b2[6] += bflo(v2.w) + bflo(v3.w); b2[7] += bfhi(v2.w) + bfhi(v3.w);
    }
    for (; k < c; ++k) {
      int r = __builtin_nontemporal_load(csr_src + s + k);
      uint4 v = inh[(size_t)r * 8 + q];
      a[0] += bflo(v.x); a[1] += bfhi(v.x); a[2] += bflo(v.y); a[3] += bfhi(v.y);
      a[4] += bflo(v.z); a[5] += bfhi(v.z); a[6] += bflo(v.w); a[7] += bfhi(v.w);
    }
    float4 s0 = make_float4(dv * (a[0] + b2[0]), dv * (a[1] + b2[1]),
                            dv * (a[2] + b2[2]), dv * (a[3] + b2[3]));
    float4 s1 = make_float4(dv * (a[4] + b2[4]), dv * (a[5] + b2[5]),
                            dv * (a[6] + b2[6]), dv * (a[7] + b2[7]));
    *(float4*)(Ss + nl * XS_LD + q * 8 + 0) = s0;
    *(float4*)(Ss + nl * XS_LD + q * 8 + 4) = s1;
  }
  __syncthreads();

  float4 o0 = ((const float4*)bias)[q * 2 + 0];
  float4 o1 = ((const float4*)bias)[q * 2 + 1];
#pragma unroll 16
  for (int k = 0; k < DF; ++k) {
    const float sk = Ss[nl * XS_LD + k];
    const float4 w0 = *(const float4*)(Ws + k * XS_LD + q * 8 + 0);
    const float4 w1 = *(const float4*)(Ws + k * XS_LD + q * 8 + 4);
    o0.x += sk * w0.x; o0.y += sk * w0.y; o0.z += sk * w0.z; o0.w += sk * w0.w;
    o1.x += sk * w1.x; o1.y += sk * w1.y; o1.z += sk * w1.z; o1.w += sk * w1.w;
  }
  if (valid) {
    o0.x = fmaxf(o0.x, 0.f); o0.y = fmaxf(o0.y, 0.f);
    o0.z = fmaxf(o0.z, 0.f); o0.w = fmaxf(o0.w, 0.f);
    o1.x = fmaxf(o1.x, 0.f); o1.y = fmaxf(o1.y, 0.f);
    o1.z = fmaxf(o1.z, 0.f); o1.w = fmaxf(o1.w, 0.f);
    if (OUTBF) {
      uint4 u;
      u.x = (unsigned int)f2bf(dv * o0.x) | ((unsigned int)f2bf(dv * o0.y) << 16);
      u.y = (unsigned int)f2bf(dv * o0.z) | ((unsigned int)f2bf(dv * o0.w) << 16);
      u.z = (unsigned int)f2bf(dv * o1.x) | ((unsigned int)f2bf(dv * o1.y) << 16);
      u.w = (unsigned int)f2bf(dv * o1.z) | ((unsigned int)f2bf(dv * o1.w) << 16);
      ((uint4*)outp)[(size_t)node * 8 + q] = u;
    } else {
      ((float4*)outp)[(size_t)node * 16 + q * 2 + 0] = o0;
      ((float4*)outp)[(size_t)node * 16 + q * 2 + 1] = o1;
    }
  }
}

extern "C" void kernel_launch(void* const* d_in, const int* in_sizes, int n_in,
                              void* d_out, int out_size, void* d_ws, size_t ws_size,
                              hipStream_t stream) {
  const float* x  = (const float*)d_in[0];
  const float* W1 = (const float*)d_in[1];
  const float* b1 = (const float*)d_in[2];
  const float* W2 = (const float*)d_in[3];
  const float* b2 = (const float*)d_in[4];
  const int*   ei = (const int*)d_in[5];

  const int n = in_sizes[0] / DF;        // 50000
  const int E = in_sizes[5] / 2;         // 800000
  const int* rows = ei;
  const int* cols = ei + E;
  const int nb = (n + 255) >> 8;         // 196 buckets
  const int eblocks = (E + ECHUNK - 1) / ECHUNK;

  char* w = (char*)d_ws;
  size_t off = 0;
  auto alloc = [&](size_t bytes) { char* p = w + off; off = (off + bytes + 255) & ~(size_t)255; return p; };
  float* dinv    = (float*)alloc((size_t)n * 4);
  int*   cntp    = (int*)  alloc((size_t)n * 4);
  int*   basep   = (int*)  alloc((size_t)n * 4);
  int*   permp   = (int*)  alloc((size_t)n * 4);
  int*   gcursor = (int*)  alloc(256 * 4);
  unsigned int* bfile = (unsigned int*)alloc((size_t)nb * BCAP * 4);
  int*   csr_src = (int*)  alloc((size_t)nb * BCAP * 4);
  uint4* xh      = (uint4*)alloc((size_t)n * DF * 2);   // 6.4 MB bf16
  uint4* zh      = (uint4*)alloc((size_t)n * DF * 2);   // 6.4 MB bf16

  const int b256 = 256;

  // ---- CSR build + dinv + degree-sorted perm ----
  init_cur_k<<<1, 256, 0, stream>>>(gcursor);
  part_k<<<eblocks, b256, 0, stream>>>(rows, cols, gcursor, bfile, E);
  bucket_k<<<nb, b256, 0, stream>>>(bfile, gcursor, csr_src, basep, cntp, dinv, permp, n);

  // ---- convert x -> xh = bf16(dinv*x) ----
  conv_k<<<(n * 8 + 255) / 256, b256, 0, stream>>>(x, dinv, xh, n);

  const int lay_blocks = (n + 31) / 32;   // 1563

  // ---- layer 1: xh -> zh (bf16, prescaled) ----
  fused_layer_k<1><<<lay_blocks, b256, 0, stream>>>(xh, W1, b1, csr_src, basep, cntp, dinv, permp, zh, n);
  // ---- layer 2: zh -> d_out (fp32) ----
  fused_layer_k<0><<<lay_blocks, b256, 0, stream>>>(zh, W2, b2, csr_src, basep, cntp, dinv, permp, d_out, n);
}

// Round 14
// 95.373 us; speedup vs baseline: 1.5375x; 1.0711x over previous
//
#include <hip/hip_runtime.h>

// GCN 2-layer forward, aggregate-first + bf16 dinv-prescaled gather.
//   xh[r] = bf16(dinv_r * in_r);  S_c = dinv_c * sum xh_r;  z = relu(S@W + b)
// Gather loop: coalesced 8-wide index blocks, shfl-broadcast, idx double-buffer,
// 8 independent row loads in flight per 8-lane group.
// CSR via counting sort into fixed-capacity bucket regions (bucket = col>>8).

#define DF 64
#define XS_LD 68
#define ECHUNK 4096
#define BCAP 5120        // bucket region capacity (mean 4096 + 16 sigma)

__device__ __forceinline__ unsigned short f2bf(float f) {
  union { float f; unsigned int u; } c; c.f = f;
  unsigned int r = c.u + 0x7FFFu + ((c.u >> 16) & 1u);   // RNE
  return (unsigned short)(r >> 16);
}
__device__ __forceinline__ float bflo(unsigned int u) {
  union { unsigned int u; float f; } c; c.u = u << 16; return c.f;
}
__device__ __forceinline__ float bfhi(unsigned int u) {
  union { unsigned int u; float f; } c; c.u = u & 0xFFFF0000u; return c.f;
}

// ---- stage 0: init bucket cursors ----
__global__ void init_cur_k(int* __restrict__ gcursor) {
  gcursor[threadIdx.x] = threadIdx.x * BCAP;
}

// ---- stage 1: partition edges into bucket regions (direct-index flush) ----
__global__ __launch_bounds__(256) void part_k(
    const int* __restrict__ rows, const int* __restrict__ cols,
    int* __restrict__ gcursor, unsigned int* __restrict__ bfile, int e_cnt)
{
  __shared__ int h[256];
  __shared__ int p[256];
  __shared__ int lb[256];
  __shared__ int cur[256];
  __shared__ int gb[256];
  __shared__ unsigned int buf[ECHUNK];
  const int tid = threadIdx.x;
  h[tid] = 0; __syncthreads();

  const int e0 = blockIdx.x * ECHUNK;
  const int m  = min(ECHUNK, e_cnt - e0);
  unsigned int pk[ECHUNK / 256];
  int bk[ECHUNK / 256];
#pragma unroll
  for (int j = 0; j < ECHUNK / 256; ++j) {
    int idx = j * 256 + tid;
    if (idx < m) {
      int c = cols[e0 + idx];
      int r = rows[e0 + idx];
      bk[j] = c >> 8;
      // bucket in [31:24], local col in [23:16], row in [15:0]
      pk[j] = ((unsigned int)bk[j] << 24) | ((unsigned int)(c & 255) << 16) | (unsigned int)r;
      atomicAdd(&h[bk[j]], 1);
    } else bk[j] = -1;
  }
  __syncthreads();

  const int myc = h[tid];
  p[tid] = myc; __syncthreads();
  for (int off = 1; off < 256; off <<= 1) {
    int t = (tid >= off) ? p[tid - off] : 0;
    __syncthreads();
    p[tid] += t;
    __syncthreads();
  }
  const int ex = p[tid] - myc;
  lb[tid] = ex; cur[tid] = ex;
  if (myc > 0) gb[tid] = atomicAdd(&gcursor[tid], myc);
  __syncthreads();

#pragma unroll
  for (int j = 0; j < ECHUNK / 256; ++j)
    if (bk[j] >= 0) { int pos = atomicAdd(&cur[bk[j]], 1); buf[pos] = pk[j]; }
  __syncthreads();

  for (int i = tid; i < m; i += 256) {
    unsigned int v = buf[i];
    int b = (int)(v >> 24);
    bfile[gb[b] + (i - lb[b])] = v;
  }
}

// ---- stage 2: per-bucket counting sort -> csr_src, cnt, base, dinv ----
__global__ __launch_bounds__(256) void bucket_k(
    const unsigned int* __restrict__ bfile, const int* __restrict__ gcursor,
    int* __restrict__ csr_src, int* __restrict__ basep, int* __restrict__ cntp,
    float* __restrict__ dinv, int n)
{
  __shared__ unsigned int ein[BCAP];
  __shared__ unsigned short eout[BCAP];
  __shared__ int h[256];
  __shared__ int p[256];
  __shared__ int cur[256];
  const int tid = threadIdx.x;
  const int b   = blockIdx.x;
  const int s   = b * BCAP;
  int L = gcursor[b] - s;
  if (L > BCAP) L = BCAP;

  for (int i = tid; i < L; i += 256) ein[i] = bfile[s + i];
  h[tid] = 0; __syncthreads();
  for (int i = tid; i < L; i += 256) atomicAdd(&h[(ein[i] >> 16) & 255], 1);
  __syncthreads();

  const int myc = h[tid];
  p[tid] = myc; __syncthreads();
  for (int off = 1; off < 256; off <<= 1) {
    int t = (tid >= off) ? p[tid - off] : 0;
    __syncthreads();
    p[tid] += t;
    __syncthreads();
  }
  const int ex = p[tid] - myc;
  cur[tid] = ex;
  __syncthreads();

  for (int i = tid; i < L; i += 256) {
    unsigned int pk = ein[i];
    int pos = atomicAdd(&cur[(pk >> 16) & 255], 1);
    eout[pos] = (unsigned short)(pk & 0xffffu);
  }
  __syncthreads();

  for (int i = tid; i < L; i += 256) csr_src[s + i] = (int)eout[i];

  const int node = b * 256 + tid;
  if (node < n) {
    basep[node] = s + ex;
    cntp[node]  = myc;
    dinv[node]  = rsqrtf(1.0f + (float)myc);
  }
}

// ---- stage 3: xh = bf16(dinv * x), packed 8 per thread ----
__global__ __launch_bounds__(256) void conv_k(
    const float* __restrict__ x, const float* __restrict__ dinv,
    uint4* __restrict__ xh, int n)
{
  int t = blockIdx.x * blockDim.x + threadIdx.x;   // over n*8 slots
  if (t >= n * 8) return;
  const float dv = dinv[t >> 3];
  float4 v0 = ((const float4*)x)[(size_t)t * 2 + 0];
  float4 v1 = ((const float4*)x)[(size_t)t * 2 + 1];
  uint4 o;
  o.x = (unsigned int)f2bf(dv * v0.x) | ((unsigned int)f2bf(dv * v0.y) << 16);
  o.y = (unsigned int)f2bf(dv * v0.z) | ((unsigned int)f2bf(dv * v0.w) << 16);
  o.z = (unsigned int)f2bf(dv * v1.x) | ((unsigned int)f2bf(dv * v1.y) << 16);
  o.w = (unsigned int)f2bf(dv * v1.z) | ((unsigned int)f2bf(dv * v1.w) << 16);
  xh[t] = o;
}

#define ACC8(acc, v) \
  acc[0] += bflo(v.x); acc[1] += bfhi(v.x); acc[2] += bflo(v.y); acc[3] += bfhi(v.y); \
  acc[4] += bflo(v.z); acc[5] += bfhi(v.z); acc[6] += bflo(v.w); acc[7] += bfhi(v.w);

// ---- fused layer: bf16 gather (8 lanes/node, 16B/lane), fp32 accum,
//      S tile -> LDS, in-block GEMM + bias + relu. 32 nodes / 256-thr block.
//      Gather: 8-wide coalesced idx block + shfl broadcast + idx double-buffer.
//      OUTBF=1: write bf16(dinv_c * relu) for next layer; else fp32. ----
template<int OUTBF>
__global__ __launch_bounds__(256) void fused_layer_k(
    const uint4* __restrict__ inh, const float* __restrict__ W,
    const float* __restrict__ bias, const int* __restrict__ csr_src,
    const int* __restrict__ basep, const int* __restrict__ cntp,
    const float* __restrict__ dinv, void* __restrict__ outp, int n)
{
  __shared__ float Ws[DF * XS_LD];
  __shared__ float Ss[32 * XS_LD];
  const int tid = threadIdx.x;

#pragma unroll
  for (int i = 0; i < 4; ++i) {
    const int f4 = tid + 256 * i;
    const int k  = f4 >> 4;
    const int c0 = (f4 & 15) * 4;
    *(float4*)(Ws + k * XS_LD + c0) = *(const float4*)(W + (size_t)f4 * 4);
  }

  const int nl   = tid >> 3;            // 0..31
  const int q    = tid & 7;             // 0..7
  const int node = blockIdx.x * 32 + nl;
  const bool valid = (node < n);
  float dv = 0.f;

  if (valid) {
    float a[8] = {0,0,0,0,0,0,0,0};
    float b2[8] = {0,0,0,0,0,0,0,0};
    dv = dinv[node];
    {
      uint4 v = inh[(size_t)node * 8 + q];          // self term (prescaled)
      ACC8(a, v)
    }
    const int s = basep[node], c = cntp[node];
    int k = 0;
    if (c >= 8) {
      int idxv = csr_src[s + q];                    // lane q holds idx k+q
      while (k + 8 <= c) {
        const int kn = k + 8;
        int idxn = 0;
        if (kn + 8 <= c) idxn = csr_src[s + kn + q];  // prefetch next block
        const int r0 = __shfl(idxv, 0, 8), r1 = __shfl(idxv, 1, 8);
        const int r2 = __shfl(idxv, 2, 8), r3 = __shfl(idxv, 3, 8);
        const int r4 = __shfl(idxv, 4, 8), r5 = __shfl(idxv, 5, 8);
        const int r6 = __shfl(idxv, 6, 8), r7 = __shfl(idxv, 7, 8);
        uint4 v0 = inh[(size_t)r0 * 8 + q];
        uint4 v1 = inh[(size_t)r1 * 8 + q];
        uint4 v2 = inh[(size_t)r2 * 8 + q];
        uint4 v3 = inh[(size_t)r3 * 8 + q];
        uint4 v4 = inh[(size_t)r4 * 8 + q];
        uint4 v5 = inh[(size_t)r5 * 8 + q];
        uint4 v6 = inh[(size_t)r6 * 8 + q];
        uint4 v7 = inh[(size_t)r7 * 8 + q];
        ACC8(a, v0) ACC8(b2, v1) ACC8(a, v2) ACC8(b2, v3)
        ACC8(a, v4) ACC8(b2, v5) ACC8(a, v6) ACC8(b2, v7)
        idxv = idxn; k = kn;
      }
    }
    for (; k < c; ++k) {                            // tail, <8 edges
      int r = csr_src[s + k];
      uint4 v = inh[(size_t)r * 8 + q];
      ACC8(a, v)
    }
    float4 s0 = make_float4(dv * (a[0] + b2[0]), dv * (a[1] + b2[1]),
                            dv * (a[2] + b2[2]), dv * (a[3] + b2[3]));
    float4 s1 = make_float4(dv * (a[4] + b2[4]), dv * (a[5] + b2[5]),
                            dv * (a[6] + b2[6]), dv * (a[7] + b2[7]));
    *(float4*)(Ss + nl * XS_LD + q * 8 + 0) = s0;
    *(float4*)(Ss + nl * XS_LD + q * 8 + 4) = s1;
  }
  __syncthreads();

  float4 o0 = ((const float4*)bias)[q * 2 + 0];
  float4 o1 = ((const float4*)bias)[q * 2 + 1];
#pragma unroll 16
  for (int k = 0; k < DF; ++k) {
    const float sk = Ss[nl * XS_LD + k];
    const float4 w0 = *(const float4*)(Ws + k * XS_LD + q * 8 + 0);
    const float4 w1 = *(const float4*)(Ws + k * XS_LD + q * 8 + 4);
    o0.x += sk * w0.x; o0.y += sk * w0.y; o0.z += sk * w0.z; o0.w += sk * w0.w;
    o1.x += sk * w1.x; o1.y += sk * w1.y; o1.z += sk * w1.z; o1.w += sk * w1.w;
  }
  if (valid) {
    o0.x = fmaxf(o0.x, 0.f); o0.y = fmaxf(o0.y, 0.f);
    o0.z = fmaxf(o0.z, 0.f); o0.w = fmaxf(o0.w, 0.f);
    o1.x = fmaxf(o1.x, 0.f); o1.y = fmaxf(o1.y, 0.f);
    o1.z = fmaxf(o1.z, 0.f); o1.w = fmaxf(o1.w, 0.f);
    if (OUTBF) {
      uint4 u;
      u.x = (unsigned int)f2bf(dv * o0.x) | ((unsigned int)f2bf(dv * o0.y) << 16);
      u.y = (unsigned int)f2bf(dv * o0.z) | ((unsigned int)f2bf(dv * o0.w) << 16);
      u.z = (unsigned int)f2bf(dv * o1.x) | ((unsigned int)f2bf(dv * o1.y) << 16);
      u.w = (unsigned int)f2bf(dv * o1.z) | ((unsigned int)f2bf(dv * o1.w) << 16);
      ((uint4*)outp)[(size_t)node * 8 + q] = u;
    } else {
      ((float4*)outp)[(size_t)node * 16 + q * 2 + 0] = o0;
      ((float4*)outp)[(size_t)node * 16 + q * 2 + 1] = o1;
    }
  }
}

extern "C" void kernel_launch(void* const* d_in, const int* in_sizes, int n_in,
                              void* d_out, int out_size, void* d_ws, size_t ws_size,
                              hipStream_t stream) {
  const float* x  = (const float*)d_in[0];
  const float* W1 = (const float*)d_in[1];
  const float* b1 = (const float*)d_in[2];
  const float* W2 = (const float*)d_in[3];
  const float* b2 = (const float*)d_in[4];
  const int*   ei = (const int*)d_in[5];

  const int n = in_sizes[0] / DF;        // 50000
  const int E = in_sizes[5] / 2;         // 800000
  const int* rows = ei;
  const int* cols = ei + E;
  const int nb = (n + 255) >> 8;         // 196 buckets
  const int eblocks = (E + ECHUNK - 1) / ECHUNK;

  char* w = (char*)d_ws;
  size_t off = 0;
  auto alloc = [&](size_t bytes) { char* p = w + off; off = (off + bytes + 255) & ~(size_t)255; return p; };
  float* dinv    = (float*)alloc((size_t)n * 4);
  int*   cntp    = (int*)  alloc((size_t)n * 4);
  int*   basep   = (int*)  alloc((size_t)n * 4);
  int*   gcursor = (int*)  alloc(256 * 4);
  unsigned int* bfile = (unsigned int*)alloc((size_t)nb * BCAP * 4);
  int*   csr_src = (int*)  alloc((size_t)nb * BCAP * 4);
  uint4* xh      = (uint4*)alloc((size_t)n * DF * 2);   // 6.4 MB bf16
  uint4* zh      = (uint4*)alloc((size_t)n * DF * 2);   // 6.4 MB bf16

  const int b256 = 256;

  // ---- CSR build + dinv ----
  init_cur_k<<<1, 256, 0, stream>>>(gcursor);
  part_k<<<eblocks, b256, 0, stream>>>(rows, cols, gcursor, bfile, E);
  bucket_k<<<nb, b256, 0, stream>>>(bfile, gcursor, csr_src, basep, cntp, dinv, n);

  // ---- convert x -> xh = bf16(dinv*x) ----
  conv_k<<<(n * 8 + 255) / 256, b256, 0, stream>>>(x, dinv, xh, n);

  const int lay_blocks = (n + 31) / 32;   // 1563

  // ---- layer 1: xh -> zh (bf16, prescaled) ----
  fused_layer_k<1><<<lay_blocks, b256, 0, stream>>>(xh, W1, b1, csr_src, basep, cntp, dinv, zh, n);
  // ---- layer 2: zh -> d_out (fp32) ----
  fused_layer_k<0><<<lay_blocks, b256, 0, stream>>>(zh, W2, b2, csr_src, basep, cntp, dinv, d_out, n);
}